// Round 12
// baseline (111.834 us; speedup 1.0000x reference)
//
#include <hip/hip_runtime.h>

#define N_NODES 50000
#define N_EDGES 800000
#define D_IN    128
#define CAP     64     // max degree ~40 for Binomial(800k, 1/50k)
#define CNT_STRIDE 16  // 1 counter per 64B line

#define NPART   8                        // partition = t & 7
#define PART_SZ (N_NODES / NPART)        // 6250 (exact: 50000 = 6250*8)
#define NSUB    8                        // contention-spreading sub-tag (blockIdx&7)
#define SUBCAP  16384                    // per (part,sub) staging cap (mean 12.5k, +36 sigma)
#define SPLIT_BLOCKS  ((N_EDGES + 1023) / 1024)          // 782
#define BUCKET_BLOCKS (NPART * NSUB * (SUBCAP / 256))    // 4096
#define CVT_BLOCKS    ((N_NODES + 3) / 4)                // 12500
#define AGG_BLOCKS    (((PART_SZ + 3) / 4) * NPART)      // 12504

#define ZERO_INTS (N_NODES * CNT_STRIDE + NPART * NSUB * 16)  // 801024
#define ZERO_INT4 (ZERO_INTS / 4)                              // 200256

// ---------------------------------------------------------------------------
// Ballot-split two-phase bucket sort + bf16 gather.
//  k_zero      : cnt+gctr zeroing at streaming BW
//  k_split     : read edges ONCE; wave-ballot multi-split by t&7; ONE leader
//                atomic per wave-group (max 8/wave, not 64); grouped stores
//  k_bucket_cvt: phase B (XCD-local bucket atomics) fused with bf16 cvt
//  k_agg       : XCD-aligned (node = local*8 + part), 8-deep MLP gather
//
// ws: cnt[N*16] 3.2MB | gctr[64*16] 4KB | staging[64*SUBCAP] u32 4MB |
//     sorted16[N*CAP] u16 6.4MB | Xh[N*128] u16 12.8MB | selfdot[N] f32 200KB
// ---------------------------------------------------------------------------

__device__ __forceinline__ unsigned short f32_to_bf16_rn(float f) {
    unsigned int u = __float_as_uint(f);
    u += 0x7fffu + ((u >> 16) & 1u);      // round-to-nearest-even
    return (unsigned short)(u >> 16);
}

__global__ __launch_bounds__(256) void k_zero(int4* __restrict__ p)
{
    int idx = blockIdx.x * 256 + threadIdx.x;
    if (idx < ZERO_INT4) p[idx] = make_int4(0, 0, 0, 0);
}

__global__ __launch_bounds__(256) void k_split(
    const int* __restrict__ src,
    const int* __restrict__ dst,
    int*       __restrict__ gctr,
    unsigned int* __restrict__ staging)
{
    int tid  = threadIdx.x;
    int lane = tid & 63;
    int sub  = blockIdx.x & (NSUB - 1);
    int base = blockIdx.x * 1024;
#pragma unroll
    for (int k = 0; k < 4; ++k) {
        int e = base + (k << 8) + tid;
        // N_EDGES % 64 == 0 -> this guard is wave-uniform (ballots safe)
        if (e < N_EDGES) {
            int t = dst[e];
            int s = src[e];
            int p = t & 7;
            unsigned long long b0 = __ballot(p & 1);
            unsigned long long b1 = __ballot(p & 2);
            unsigned long long b2 = __ballot(p & 4);
            unsigned long long mm = ((p & 1) ? b0 : ~b0)
                                  & ((p & 2) ? b1 : ~b1)
                                  & ((p & 4) ? b2 : ~b2);
            int rank   = __popcll(mm & ((1ull << lane) - 1ull));
            int leader = __ffsll((long long)mm) - 1;
            int grp    = __popcll(mm);
            int bpos = 0;
            if (lane == leader)
                bpos = atomicAdd(&gctr[(p * NSUB + sub) * 16], grp);
            bpos = __shfl(bpos, leader);
            int pos = bpos + rank;
            if (pos < SUBCAP) {
                unsigned int rec = ((unsigned int)(t >> 3) << 16) | (unsigned int)s;
                staging[(size_t)(p * NSUB + sub) * SUBCAP + pos] = rec;
            }
        }
    }
}

// Phase B (bucket, blocks [0, BUCKET_BLOCKS)): part = blockIdx&7 == XCD ->
// cnt/sorted16 atomics+stores stay L2-local. Fused cvt role after.
__global__ __launch_bounds__(256) void k_bucket_cvt(
    const unsigned int* __restrict__ staging,
    const int*   __restrict__ gctr,
    int*         __restrict__ cnt,
    unsigned short* __restrict__ sorted16,
    const float* __restrict__ X,
    const float* __restrict__ W_r,
    const float* __restrict__ b_l,
    unsigned short* __restrict__ Xh,
    float*       __restrict__ selfdot)
{
    int b = blockIdx.x;
    if (b < BUCKET_BLOCKS) {
        int part  = b & 7;
        int sub   = (b >> 3) & 7;
        int chunk = b >> 6;                    // 0..SUBCAP/256-1
        int cidx  = part * NSUB + sub;
        int count = gctr[cidx * 16];
        if (count > SUBCAP) count = SUBCAP;
        int idx = chunk * 256 + threadIdx.x;
        if (idx < count) {
            unsigned int rec = staging[(size_t)cidx * SUBCAP + idx];
            int t = ((int)(rec >> 16) << 3) | part;
            int pos = atomicAdd(&cnt[t * CNT_STRIDE], 1);
            if (pos < CAP)
                sorted16[t * CAP + pos] = (unsigned short)(rec & 0xffffu);
        }
        return;
    }
    // cvt role: one wave per row -> bf16 row + selfdot = W_r.x + b_l
    int wave = ((b - BUCKET_BLOCKS) * 256 + threadIdx.x) >> 6;
    int lane = threadIdx.x & 63;
    if (wave >= N_NODES) return;

    float2 x = ((const float2*)(X + (size_t)wave * D_IN))[lane];
    unsigned int packed = ((unsigned int)f32_to_bf16_rn(x.y) << 16)
                        |  (unsigned int)f32_to_bf16_rn(x.x);
    ((unsigned int*)(Xh + (size_t)wave * D_IN))[lane] = packed;

    float2 wr = ((const float2*)W_r)[lane];
    float acc = x.x * wr.x + x.y * wr.y;
#pragma unroll
    for (int off = 32; off; off >>= 1)
        acc += __shfl_down(acc, off);
    if (lane == 0)
        selfdot[wave] = acc + b_l[0];
}

#define GATHER(mm, ss)                                                \
    {                                                                 \
        unsigned int u = Xu[(size_t)(ss) * 64 + lane];                \
        (mm).x = fmaxf((mm).x, __uint_as_float(u << 16));             \
        (mm).y = fmaxf((mm).y, __uint_as_float(u & 0xffff0000u));     \
    }

// One wave per node, XCD-aligned: node = local*8 + part (part = blockIdx&7),
// so cnt/sorted16 reads hit the L2 that k_bucket wrote them into.
__global__ __launch_bounds__(256) void k_agg(
    const unsigned short* __restrict__ Xh,
    const int*   __restrict__ cnt,
    const unsigned short* __restrict__ sorted16,
    const float* __restrict__ W_l,
    const float* __restrict__ selfdot,
    float*       __restrict__ out)
{
    int part  = blockIdx.x & (NPART - 1);
    int local = (blockIdx.x >> 3) * 4 + (threadIdx.x >> 6);
    int lane  = threadIdx.x & 63;
    if (local >= PART_SZ) return;
    int wave = local * 8 + part;

    // independent loads -> in flight together
    int n = cnt[wave * CNT_STRIDE];
    int sid = (int)sorted16[wave * CAP + lane];   // lanes >= n never consumed
    if (n > CAP) n = CAP;

    float2 wl = ((const float2*)W_l)[lane];
    float sd  = selfdot[wave];

    const unsigned int* Xu = (const unsigned int*)Xh;
    float2 m[8];
#pragma unroll
    for (int k = 0; k < 8; ++k) m[k] = make_float2(-INFINITY, -INFINITY);

    int i = 0;
    for (; i + 8 <= n; i += 8) {
        int s0 = __shfl(sid, i + 0), s1 = __shfl(sid, i + 1);
        int s2 = __shfl(sid, i + 2), s3 = __shfl(sid, i + 3);
        int s4 = __shfl(sid, i + 4), s5 = __shfl(sid, i + 5);
        int s6 = __shfl(sid, i + 6), s7 = __shfl(sid, i + 7);
        GATHER(m[0], s0) GATHER(m[1], s1) GATHER(m[2], s2) GATHER(m[3], s3)
        GATHER(m[4], s4) GATHER(m[5], s5) GATHER(m[6], s6) GATHER(m[7], s7)
    }
    if (i + 4 <= n) {
        int s0 = __shfl(sid, i + 0), s1 = __shfl(sid, i + 1);
        int s2 = __shfl(sid, i + 2), s3 = __shfl(sid, i + 3);
        GATHER(m[0], s0) GATHER(m[1], s1) GATHER(m[2], s2) GATHER(m[3], s3)
        i += 4;
    }
    if (i + 2 <= n) {
        int s0 = __shfl(sid, i + 0), s1 = __shfl(sid, i + 1);
        GATHER(m[0], s0) GATHER(m[1], s1)
        i += 2;
    }
    if (i < n) {
        int s0 = __shfl(sid, i);
        GATHER(m[0], s0)
    }
#pragma unroll
    for (int k = 4; k; k >>= 1)
#pragma unroll
        for (int j = 0; j < k; ++j) {
            m[j].x = fmaxf(m[j].x, m[j + k].x);
            m[j].y = fmaxf(m[j].y, m[j + k].y);
        }
    if (n == 0) { m[0].x = 0.0f; m[0].y = 0.0f; }   // segment_max empty fill

    float acc = m[0].x * wl.x + m[0].y * wl.y;
#pragma unroll
    for (int off = 32; off; off >>= 1)
        acc += __shfl_down(acc, off);
    if (lane == 0)
        out[wave] = acc + sd;
}

extern "C" void kernel_launch(void* const* d_in, const int* in_sizes, int n_in,
                              void* d_out, int out_size, void* d_ws, size_t ws_size,
                              hipStream_t stream)
{
    const float* X   = (const float*)d_in[0];   // [N_NODES, D_IN]
    const float* W_l = (const float*)d_in[1];   // [1, D_IN]
    const float* b_l = (const float*)d_in[2];   // [1]
    const float* W_r = (const float*)d_in[3];   // [1, D_IN]
    const int*   ei  = (const int*)d_in[4];     // [2, N_EDGES]
    const int*   src = ei;
    const int*   dst = ei + N_EDGES;

    int* cnt  = (int*)d_ws;                                        // 3.2 MB
    int* gctr = cnt + (size_t)N_NODES * CNT_STRIDE;                // 4 KB
    unsigned int* staging = (unsigned int*)(gctr + NPART * NSUB * 16); // 4 MB
    unsigned short* sorted16 =
        (unsigned short*)(staging + (size_t)NPART * NSUB * SUBCAP);    // 6.4 MB
    unsigned short* Xh = sorted16 + (size_t)N_NODES * CAP;         // 12.8 MB
    float* selfdot = (float*)(Xh + (size_t)N_NODES * D_IN);        // 200 KB
    float* out = (float*)d_out;

    k_zero      <<<(ZERO_INT4 + 255) / 256, 256, 0, stream>>>((int4*)d_ws);
    k_split     <<<SPLIT_BLOCKS, 256, 0, stream>>>(src, dst, gctr, staging);
    k_bucket_cvt<<<BUCKET_BLOCKS + CVT_BLOCKS, 256, 0, stream>>>(
        staging, gctr, cnt, sorted16, X, W_r, b_l, Xh, selfdot);
    k_agg       <<<AGG_BLOCKS, 256, 0, stream>>>(
        Xh, cnt, sorted16, W_l, selfdot, out);
}

// Round 13
// 76.476 us; speedup vs baseline: 1.4624x; 1.4624x over previous
//
#include <hip/hip_runtime.h>

#define N_NODES 50000
#define N_EDGES 800000
#define D_IN    128
#define CAP     64     // max degree ~40 for Binomial(800k, 1/50k)
#define CNT_STRIDE 16  // 1 counter per 64B line

#define NPART   8                                  // = # XCDs
#define PART_SZ (N_NODES / NPART)                  // 6250 (exact)
#define ECHUNK  2048                               // edges per scatter block
#define N_CHUNKS ((N_EDGES + ECHUNK - 1) / ECHUNK) // 391
#define SCT_BLOCKS (N_CHUNKS * NPART)              // 3128
#define CVT_BLOCKS ((N_NODES * 64 + 255) / 256)    // 12500

#define ZERO_INT4 ((N_NODES * CNT_STRIDE) / 4)     // 200000

// ---------------------------------------------------------------------------
// Round 13 = round 9 (79.1us, best) + k_zero (runtime fill kernel measured at
// 70 GB/s / 8% occupancy) + XCD-aligned k_agg + unconditional id-list load.
// Scatter phase is transaction-rate-bound (~46us invariant across 5 variants);
// keep its best-known form (fused with cvt, XCD-partitioned re-scan).
//
// ws layout:
//   cnt      int [N_NODES*16]      degree/cursor, 1 per 64B line (3.2 MB)
//   sorted16 u16 [N_NODES*CAP]     src ids, segment i at i*CAP   (6.4 MB)
//   Xh       u16 [N_NODES*D_IN]    bf16(X)                       (12.8 MB)
//   selfdot  f32 [N_NODES]         W_r . x_i + b_l
// ---------------------------------------------------------------------------

__device__ __forceinline__ unsigned short f32_to_bf16_rn(float f) {
    unsigned int u = __float_as_uint(f);
    u += 0x7fffu + ((u >> 16) & 1u);      // round-to-nearest-even
    return (unsigned short)(u >> 16);
}

__global__ __launch_bounds__(256) void k_zero(int4* __restrict__ p)
{
    int idx = blockIdx.x * 256 + threadIdx.x;
    if (idx < ZERO_INT4) p[idx] = make_int4(0, 0, 0, 0);
}

__global__ __launch_bounds__(256) void k_prep(
    const float* __restrict__ X,
    const float* __restrict__ W_r,
    const float* __restrict__ b_l,
    const int*   __restrict__ src,
    const int*   __restrict__ dst,
    int*         __restrict__ cnt,
    unsigned short* __restrict__ sorted16,
    unsigned short* __restrict__ Xh,
    float*       __restrict__ selfdot)
{
    int b = blockIdx.x;
    if (b < SCT_BLOCKS) {
        int part  = b & (NPART - 1);       // presumed XCD id (round-robin)
        int chunk = b >> 3;
        int lo = part * PART_SZ;
        int hi = lo + PART_SZ;
        int base = chunk * ECHUNK + threadIdx.x;
#pragma unroll
        for (int k = 0; k < ECHUNK / 256; ++k) {
            int e = base + (k << 8);
            if (e < N_EDGES) {
                int t = dst[e];
                if (t >= lo && t < hi) {
                    int p = atomicAdd(&cnt[t * CNT_STRIDE], 1);
                    if (p < CAP)
                        sorted16[t * CAP + p] = (unsigned short)src[e];
                }
            }
        }
        return;
    }
    // convert role: one wave per row -> bf16 row + selfdot = W_r.x + b_l
    int wave = ((b - SCT_BLOCKS) * 256 + threadIdx.x) >> 6;
    int lane = threadIdx.x & 63;
    if (wave >= N_NODES) return;

    float2 x = ((const float2*)(X + (size_t)wave * D_IN))[lane];
    unsigned int packed = ((unsigned int)f32_to_bf16_rn(x.y) << 16)
                        |  (unsigned int)f32_to_bf16_rn(x.x);
    ((unsigned int*)(Xh + (size_t)wave * D_IN))[lane] = packed;

    float2 wr = ((const float2*)W_r)[lane];
    float acc = x.x * wr.x + x.y * wr.y;
#pragma unroll
    for (int off = 32; off; off >>= 1)
        acc += __shfl_down(acc, off);
    if (lane == 0)
        selfdot[wave] = acc + b_l[0];
}

#define GATHER(mm, ss)                                                \
    {                                                                 \
        unsigned int u = Xu[(size_t)(ss) * 64 + lane];                \
        (mm).x = fmaxf((mm).x, __uint_as_float(u << 16));             \
        (mm).y = fmaxf((mm).y, __uint_as_float(u & 0xffff0000u));     \
    }

// One wave per node, XCD-aligned: node's partition (wave/PART_SZ) equals
// blockIdx&7, matching the partition k_prep's scatter wrote from the same
// XCD slot -> cnt/sorted16 reads are L2-local.
__global__ __launch_bounds__(256) void k_agg(
    const unsigned short* __restrict__ Xh,
    const int*   __restrict__ cnt,
    const unsigned short* __restrict__ sorted16,
    const float* __restrict__ W_l,
    const float* __restrict__ selfdot,
    float*       __restrict__ out)
{
    int part  = blockIdx.x & (NPART - 1);
    int local = (blockIdx.x >> 3) * 4 + (threadIdx.x >> 6);
    int lane  = threadIdx.x & 63;
    if (local >= PART_SZ) return;
    int wave = part * PART_SZ + local;

    // independent loads -> both in flight together
    int n = cnt[wave * CNT_STRIDE];
    int sid = (int)sorted16[wave * CAP + lane];   // lanes >= n never consumed
    if (n > CAP) n = CAP;

    float2 wl = ((const float2*)W_l)[lane];   // hoisted: overlaps gather latency
    float sd  = selfdot[wave];

    const unsigned int* Xu = (const unsigned int*)Xh;
    float2 m[8];
#pragma unroll
    for (int k = 0; k < 8; ++k) m[k] = make_float2(-INFINITY, -INFINITY);

    int i = 0;
    for (; i + 8 <= n; i += 8) {
        int s0 = __shfl(sid, i + 0), s1 = __shfl(sid, i + 1);
        int s2 = __shfl(sid, i + 2), s3 = __shfl(sid, i + 3);
        int s4 = __shfl(sid, i + 4), s5 = __shfl(sid, i + 5);
        int s6 = __shfl(sid, i + 6), s7 = __shfl(sid, i + 7);
        GATHER(m[0], s0) GATHER(m[1], s1) GATHER(m[2], s2) GATHER(m[3], s3)
        GATHER(m[4], s4) GATHER(m[5], s5) GATHER(m[6], s6) GATHER(m[7], s7)
    }
    if (i + 4 <= n) {
        int s0 = __shfl(sid, i + 0), s1 = __shfl(sid, i + 1);
        int s2 = __shfl(sid, i + 2), s3 = __shfl(sid, i + 3);
        GATHER(m[0], s0) GATHER(m[1], s1) GATHER(m[2], s2) GATHER(m[3], s3)
        i += 4;
    }
    if (i + 2 <= n) {
        int s0 = __shfl(sid, i + 0), s1 = __shfl(sid, i + 1);
        GATHER(m[0], s0) GATHER(m[1], s1)
        i += 2;
    }
    if (i < n) {
        int s0 = __shfl(sid, i);
        GATHER(m[0], s0)
    }
#pragma unroll
    for (int k = 4; k; k >>= 1)
#pragma unroll
        for (int j = 0; j < k; ++j) {
            m[j].x = fmaxf(m[j].x, m[j + k].x);
            m[j].y = fmaxf(m[j].y, m[j + k].y);
        }
    if (n == 0) { m[0].x = 0.0f; m[0].y = 0.0f; }   // segment_max empty fill

    float acc = m[0].x * wl.x + m[0].y * wl.y;
#pragma unroll
    for (int off = 32; off; off >>= 1)
        acc += __shfl_down(acc, off);
    if (lane == 0)
        out[wave] = acc + sd;
}

extern "C" void kernel_launch(void* const* d_in, const int* in_sizes, int n_in,
                              void* d_out, int out_size, void* d_ws, size_t ws_size,
                              hipStream_t stream)
{
    const float* X   = (const float*)d_in[0];   // [N_NODES, D_IN]
    const float* W_l = (const float*)d_in[1];   // [1, D_IN]
    const float* b_l = (const float*)d_in[2];   // [1]
    const float* W_r = (const float*)d_in[3];   // [1, D_IN]
    const int*   ei  = (const int*)d_in[4];     // [2, N_EDGES]
    const int*   src = ei;
    const int*   dst = ei + N_EDGES;

    int* cnt = (int*)d_ws;                                                  // 3.2 MB
    unsigned short* sorted16 = (unsigned short*)(cnt + (size_t)N_NODES * CNT_STRIDE); // 6.4 MB
    unsigned short* Xh = sorted16 + (size_t)N_NODES * CAP;                  // 12.8 MB
    float* selfdot = (float*)(Xh + (size_t)N_NODES * D_IN);                 // 200 KB
    float* out = (float*)d_out;

    k_zero<<<(ZERO_INT4 + 255) / 256, 256, 0, stream>>>((int4*)d_ws);
    k_prep<<<SCT_BLOCKS + CVT_BLOCKS, 256, 0, stream>>>(
        X, W_r, b_l, src, dst, cnt, sorted16, Xh, selfdot);
    k_agg<<<((PART_SZ + 3) / 4) * NPART, 256, 0, stream>>>(
        Xh, cnt, sorted16, W_l, selfdot, out);
}